// Round 1
// baseline (800.006 us; speedup 1.0000x reference)
//
#include <hip/hip_runtime.h>
#include <stdint.h>

// Causal dilated conv1d as bf16 MFMA GEMM.
//   out[b,o,t] = sum_{c,kk} W[o, c*4+kk] * x[b, c, t + 8*kk - 24]   (0 if idx<0)
// K-order permuted to kappa = kk*512 + c so that B^T rows are c-contiguous
// after an x transpose:  Xtp[b][tp][c] = (tp<24) ? 0 : bf16(x[b][c][tp-24]).
// GEMM: C[o, n=(b,t)] = sum_kappa Wq[o][kappa] * Xtp[b][t + 8*kk][c].

typedef unsigned short u16;
typedef unsigned int   u32;
typedef __attribute__((ext_vector_type(8))) __bf16 bf16x8;
typedef __attribute__((ext_vector_type(4))) float  floatx4;
typedef __attribute__((ext_vector_type(4))) u16    u16x4;

#define NB   16
#define CIN  512
#define COUT 512
#define TT   8192
#define PADT 24
#define TP   (TT + PADT)   /* 8216 rows per batch in Xtp */
#define KTOT 2048          /* CIN * KW */

__device__ __forceinline__ u16 f2bf(float f) {
  // round-to-nearest-even bf16 (inputs are finite random normals)
  u32 u = __builtin_bit_cast(u32, f);
  u += 0x7fffu + ((u >> 16) & 1u);
  return (u16)(u >> 16);
}

__device__ __forceinline__ void gl_lds16(const void* g, void* l) {
  // async 16B/lane global->LDS; LDS dest = wave-uniform base + lane*16
  __builtin_amdgcn_global_load_lds((__attribute__((address_space(1))) void*)(g),
                                   (__attribute__((address_space(3))) void*)(l),
                                   16, 0, 0);
}

// ---- Pass 0: zero the 24 pad rows of each batch in Xtp -------------------
__global__ __launch_bounds__(256) void zero_pad_k(u16* __restrict__ xt) {
  // 16 batches * 24 rows * 512 ch = 196608 u16 = 24576 * (8 u16); grid = 96*256
  int idx = blockIdx.x * 256 + threadIdx.x;
  int b   = idx / 1536;           // 24*512/8 chunks per batch
  int rem = idx - b * 1536;
  u16x4 z = (u16x4)(0);
  u16* p = xt + (size_t)b * TP * CIN + (size_t)rem * 8;
  *(u16x4*)(p)     = z;
  *(u16x4*)(p + 4) = z;
}

// ---- Pass 1: transpose + cast  x[b][c][t] -> Xtp[b][24+t][c] -------------
__global__ __launch_bounds__(256) void transpose_cast_k(const float* __restrict__ x,
                                                        u16* __restrict__ xt) {
  __shared__ u16 tile[64][68];    // [c_local][t_local], padded vs bank conflicts
  const int b  = blockIdx.z;
  const int c0 = blockIdx.y * 64;
  const int t0 = blockIdx.x * 64;
  const int tid = threadIdx.x;

  // load: 64 c-rows x 64 t floats (float4 per thread, 4 passes)
  const int t4   = tid & 15;      // which float4 in the row
  const int crow = tid >> 4;      // 0..15
#pragma unroll
  for (int p = 0; p < 4; ++p) {
    const int c = crow + p * 16;
    const float4 v = *(const float4*)(x + ((size_t)(b * CIN + c0 + c) * TT + t0 + t4 * 4));
    u16x4 h;
    h.x = f2bf(v.x); h.y = f2bf(v.y); h.z = f2bf(v.z); h.w = f2bf(v.w);
    *(u16x4*)&tile[c][t4 * 4] = h;
  }
  __syncthreads();

  // store: 64 t-rows x 64 c bf16 (8 u16 = 16B per thread, 2 passes)
  const int tl = tid >> 3;        // 0..31
  const int cs = (tid & 7) * 8;   // channel segment
#pragma unroll
  for (int p = 0; p < 2; ++p) {
    const int t = tl + p * 32;
    u32 w0 = (u32)tile[cs + 0][t] | ((u32)tile[cs + 1][t] << 16);
    u32 w1 = (u32)tile[cs + 2][t] | ((u32)tile[cs + 3][t] << 16);
    u32 w2 = (u32)tile[cs + 4][t] | ((u32)tile[cs + 5][t] << 16);
    u32 w3 = (u32)tile[cs + 6][t] | ((u32)tile[cs + 7][t] << 16);
    uint4 v; v.x = w0; v.y = w1; v.z = w2; v.w = w3;
    *(uint4*)(xt + ((size_t)b * TP + PADT + t0 + t) * CIN + c0 + cs) = v;
  }
}

// ---- Pass 2: W permute + cast  Wq[o][kk*512+c] = bf16(W[o][c*4+kk]) ------
__global__ __launch_bounds__(256) void wperm_k(const float* __restrict__ W,
                                               u16* __restrict__ Wq) {
  const int idx = blockIdx.x * 256 + threadIdx.x;   // < 512*2048, grid=4096
  const int o   = idx >> 11;
  const int kap = idx & 2047;
  const int kk  = kap >> 9;
  const int c   = kap & 511;
  Wq[idx] = f2bf(W[o * 2048 + c * 4 + kk]);
}

// ---- Pass 3: the GEMM (m97 structure: 128x128x32, 16x16x32 bf16 MFMA) ----
__global__ __launch_bounds__(256) void conv_gemm_k(const u16* __restrict__ Wq,
                                                   const u16* __restrict__ Xt,
                                                   float* __restrict__ out) {
  __shared__ u16 As[128 * 32];    // [m][kappa], 64B rows
  __shared__ u16 Bs[128 * 32];    // [n][kappa], 64B rows

  const int tid  = threadIdx.x;
  const int lane = tid & 63;
  const int wave = tid >> 6;

  const int m0 = blockIdx.x * 128;          // 4 m-tiles (fastest -> B strip reuse in L2)
  const int nb = blockIdx.y;                // 1024 n-tiles
  const int b  = nb >> 6;                   // 64 n-tiles per batch
  const int t0 = (nb & 63) * 128;

  // staging: each wave stages 32 A-rows and 32 B-rows per K-step (2 issues each)
  const int lr = lane >> 2;                 // row within 16-row group
  const int lo = (lane & 3) * 16;           // byte offset within 64B row
  const char* Ag = (const char*)Wq + ((size_t)(m0 + wave * 32 + lr) * KTOT) * 2 + lo;
  const char* Bg = (const char*)Xt + ((size_t)b * TP + t0 + wave * 32 + lr) * (CIN * 2) + lo;
  char* Al = (char*)As + wave * 2048;
  char* Bl = (char*)Bs + wave * 2048;

  // compute: 2x2 waves, each 64x64 = 4x4 MFMA tiles
  const int wm = (wave >> 1) * 64;
  const int wn = (wave & 1) * 64;
  const char* Af0 = (const char*)As + (wm + (lane & 15)) * 64 + (lane >> 4) * 16;
  const char* Bf0 = (const char*)Bs + (wn + (lane & 15)) * 64 + (lane >> 4) * 16;

  floatx4 acc[4][4];
#pragma unroll
  for (int i = 0; i < 4; ++i)
#pragma unroll
    for (int j = 0; j < 4; ++j) acc[i][j] = (floatx4)(0.0f);

  for (int kt = 0; kt < KTOT / 32; ++kt) {
    const int kap0 = kt * 32;
    const int kk   = kap0 >> 9;             // which of the 4 taps
    const int c0   = kap0 & 511;            // channel offset
    gl_lds16(Ag + (size_t)kt * 64, Al);
    gl_lds16(Ag + (size_t)kt * 64 + 16 * 4096, Al + 1024);
    const size_t boff = (size_t)kk * 8 * (CIN * 2) + c0 * 2;  // +8 rows per tap
    gl_lds16(Bg + boff, Bl);
    gl_lds16(Bg + boff + 16 * (CIN * 2), Bl + 1024);
    __syncthreads();                        // drains vmcnt before LDS reads

    bf16x8 af[4], bff[4];
#pragma unroll
    for (int i = 0; i < 4; ++i) af[i]  = *(const bf16x8*)(Af0 + i * 1024);
#pragma unroll
    for (int j = 0; j < 4; ++j) bff[j] = *(const bf16x8*)(Bf0 + j * 1024);
#pragma unroll
    for (int i = 0; i < 4; ++i)
#pragma unroll
      for (int j = 0; j < 4; ++j)
        acc[i][j] = __builtin_amdgcn_mfma_f32_16x16x32_bf16(af[i], bff[j], acc[i][j], 0, 0, 0);
    __syncthreads();                        // protect LDS for next staging
  }

  // epilogue: D layout col = lane&15, row = (lane>>4)*4 + reg  [m89-verified]
  const int dr = (lane >> 4) * 4;
  const int dc = lane & 15;
  float* outb = out + (size_t)b * COUT * TT;
#pragma unroll
  for (int i = 0; i < 4; ++i) {
#pragma unroll
    for (int j = 0; j < 4; ++j) {
      const int mm = m0 + wm + i * 16 + dr;
      const int nn = t0 + wn + j * 16 + dc;
      float* p = outb + (size_t)mm * TT + nn;
#pragma unroll
      for (int r = 0; r < 4; ++r) p[(size_t)r * TT] = acc[i][j][r];
    }
  }
}

extern "C" void kernel_launch(void* const* d_in, const int* in_sizes, int n_in,
                              void* d_out, int out_size, void* d_ws, size_t ws_size,
                              hipStream_t stream) {
  const float* x = (const float*)d_in[0];   // [16, 512, 8192]
  const float* W = (const float*)d_in[1];   // [512, 2048]
  float* out = (float*)d_out;               // [16, 512, 8192]

  // workspace: Wq bf16 [512][2048] (2 MB) then Xtp bf16 [16][8216][512] (~134.6 MB)
  u16* Wq = (u16*)d_ws;
  u16* Xt = (u16*)d_ws + (1u << 20);

  zero_pad_k      <<<dim3(96),          dim3(256), 0, stream>>>(Xt);
  transpose_cast_k<<<dim3(128, 8, 16),  dim3(256), 0, stream>>>(x, Xt);
  wperm_k         <<<dim3(4096),        dim3(256), 0, stream>>>(W, Wq);
  conv_gemm_k     <<<dim3(4, 1024),     dim3(256), 0, stream>>>(Wq, Xt, out);
}

// Round 2
// 785.467 us; speedup vs baseline: 1.0185x; 1.0185x over previous
//
#include <hip/hip_runtime.h>
#include <stdint.h>

// Causal dilated conv1d as bf16 MFMA GEMM.
//   out[b,o,t] = sum_{c,kk} W[o, c*4+kk] * x[b, c, t + 8*kk - 24]   (0 if idx<0)
// K-order permuted to kappa = kk*512 + c so that B^T rows are c-contiguous
// after an x transpose:  Xtp[b][tp][c] = (tp<24) ? 0 : bf16(x[b][c][tp-24]).
// GEMM: C[o, n=(b,t)] = sum_kappa Wq[o][kappa] * Xtp[b][t + 8*kk][c].

typedef unsigned short u16;
typedef unsigned int   u32;
typedef __attribute__((ext_vector_type(8))) __bf16 bf16x8;
typedef __attribute__((ext_vector_type(4))) float  floatx4;

#define NB   16
#define CIN  512
#define COUT 512
#define TT   8192
#define PADT 24
#define TP   (TT + PADT)   /* 8216 rows per batch in Xtp */
#define KTOT 2048          /* CIN * KW */

__device__ __forceinline__ u16 f2bf(float f) {
  // round-to-nearest-even bf16 (inputs are finite random normals)
  u32 u = __builtin_bit_cast(u32, f);
  u += 0x7fffu + ((u >> 16) & 1u);
  return (u16)(u >> 16);
}

__device__ __forceinline__ u32 pack2(float a, float b) {
  return (u32)f2bf(a) | ((u32)f2bf(b) << 16);
}

__device__ __forceinline__ void gl_lds16(const void* g, void* l) {
  // async 16B/lane global->LDS; LDS dest = wave-uniform base + lane*16
  __builtin_amdgcn_global_load_lds((__attribute__((address_space(1))) void*)(g),
                                   (__attribute__((address_space(3))) void*)(l),
                                   16, 0, 0);
}

// ---- Pass 1: transpose + cast  x[b][c][t] -> Xtp[b][24+t][c] -------------
// fp32 LDS tile (padded) -> conflict-light; pad-row zeroing fused in.
__global__ __launch_bounds__(256) void transpose_cast_k(const float* __restrict__ x,
                                                        u16* __restrict__ xt) {
  __shared__ float tile[64][68];  // stride 68 dw = 272 B (16B aligned rows)
  const int b  = blockIdx.z;
  const int c0 = blockIdx.y * 64;
  const int t0 = blockIdx.x * 64;
  const int tid = threadIdx.x;

  // fused: zero the 24 pad rows (each (t0==0, cy, b) block zeros its c-slice)
  if (blockIdx.x == 0 && tid < 192) {
    const int row = tid >> 3;         // 0..23
    const int seg = tid & 7;          // 8 x (8 u16 = 16B) per 64-ch slice
    uint4 z; z.x = z.y = z.z = z.w = 0u;
    *(uint4*)(xt + ((size_t)b * TP + row) * CIN + c0 + seg * 8) = z;
  }

  // load: 64 c-rows x 64 t floats (float4/thread, 4 passes), coalesced 256B/row
  const int t4   = tid & 15;
  const int crow = tid >> 4;          // 0..15
#pragma unroll
  for (int p = 0; p < 4; ++p) {
    const int c = crow + p * 16;
    const float4 v = *(const float4*)(x + ((size_t)(b * CIN + c0 + c) * TT + t0 + t4 * 4));
    *(float4*)&tile[c][t4 * 4] = v;
  }
  __syncthreads();

  // store: row t gets 64 bf16 channels; 8 lanes/row -> 128B contiguous segments
  const int cseg = tid & 7;           // channel group of 8
  const int tr   = tid >> 3;          // 0..31
#pragma unroll
  for (int p = 0; p < 2; ++p) {
    const int t = tr + p * 32;
    float f[8];
#pragma unroll
    for (int k = 0; k < 8; ++k) f[k] = tile[cseg * 8 + k][t];
    uint4 v;
    v.x = pack2(f[0], f[1]); v.y = pack2(f[2], f[3]);
    v.z = pack2(f[4], f[5]); v.w = pack2(f[6], f[7]);
    *(uint4*)(xt + ((size_t)b * TP + PADT + t0 + t) * CIN + c0 + cseg * 8) = v;
  }
}

// ---- Pass 2: W permute + cast  Wq[o][kk*512+c] = bf16(W[o][c*4+kk]) ------
__global__ __launch_bounds__(256) void wperm_k(const float* __restrict__ W,
                                               u16* __restrict__ Wq) {
  const int idx = blockIdx.x * 256 + threadIdx.x;   // < 512*2048, grid=4096
  const int o   = idx >> 11;
  const int kap = idx & 2047;
  const int kk  = kap >> 9;
  const int c   = kap & 511;
  Wq[idx] = f2bf(W[o * 2048 + c * 4 + kk]);
}

// ---- Pass 3: the GEMM (m97 structure: 128x128x32, 16x16x32 bf16 MFMA) ----
// 1D grid, XCD-swizzled: the 4 m-blocks sharing a B strip get ids k,k+8,k+16,k+24
// -> same XCD under round-robin dispatch -> B reuse in that XCD's L2.
__global__ __launch_bounds__(256) void conv_gemm_k(const u16* __restrict__ Wq,
                                                   const u16* __restrict__ Xt,
                                                   float* __restrict__ out) {
  __shared__ u16 As[128 * 32];    // [m][kappa], 64B rows
  __shared__ u16 Bs[128 * 32];    // [n][kappa], 64B rows

  const int tid  = threadIdx.x;
  const int lane = tid & 63;
  const int wave = tid >> 6;

  const int id   = blockIdx.x;              // 0..4095
  const int xcd  = id & 7;
  const int slot = id >> 3;
  const int m0   = (slot & 3) * 128;
  const int nb   = (slot >> 2) * 8 + xcd;   // 0..1023
  const int b    = nb >> 6;                 // 64 n-tiles per batch
  const int t0   = (nb & 63) * 128;

  // staging: each wave stages 32 A-rows and 32 B-rows per K-step (2 issues each)
  const int lr = lane >> 2;                 // row within 16-row group
  const int lo = (lane & 3) * 16;           // byte offset within 64B row
  const char* Ag = (const char*)Wq + ((size_t)(m0 + wave * 32 + lr) * KTOT) * 2 + lo;
  const char* Bg = (const char*)Xt + ((size_t)b * TP + t0 + wave * 32 + lr) * (CIN * 2) + lo;
  char* Al = (char*)As + wave * 2048;
  char* Bl = (char*)Bs + wave * 2048;

  // compute: 2x2 waves, each 64x64 = 4x4 MFMA tiles
  const int wm = (wave >> 1) * 64;
  const int wn = (wave & 1) * 64;
  const char* Af0 = (const char*)As + (wm + (lane & 15)) * 64 + (lane >> 4) * 16;
  const char* Bf0 = (const char*)Bs + (wn + (lane & 15)) * 64 + (lane >> 4) * 16;

  floatx4 acc[4][4];
#pragma unroll
  for (int i = 0; i < 4; ++i)
#pragma unroll
    for (int j = 0; j < 4; ++j) acc[i][j] = (floatx4)(0.0f);

  for (int kt = 0; kt < KTOT / 32; ++kt) {
    const int kap0 = kt * 32;
    const int kk   = kap0 >> 9;             // which of the 4 taps
    const int c0   = kap0 & 511;            // channel offset
    gl_lds16(Ag + (size_t)kt * 64, Al);
    gl_lds16(Ag + (size_t)kt * 64 + 16 * 4096, Al + 1024);
    const size_t boff = (size_t)kk * 8 * (CIN * 2) + c0 * 2;  // +8 rows per tap
    gl_lds16(Bg + boff, Bl);
    gl_lds16(Bg + boff + 16 * (CIN * 2), Bl + 1024);
    __syncthreads();                        // drains vmcnt before LDS reads

    bf16x8 af[4], bff[4];
#pragma unroll
    for (int i = 0; i < 4; ++i) af[i]  = *(const bf16x8*)(Af0 + i * 1024);
#pragma unroll
    for (int j = 0; j < 4; ++j) bff[j] = *(const bf16x8*)(Bf0 + j * 1024);
#pragma unroll
    for (int i = 0; i < 4; ++i)
#pragma unroll
      for (int j = 0; j < 4; ++j)
        acc[i][j] = __builtin_amdgcn_mfma_f32_16x16x32_bf16(af[i], bff[j], acc[i][j], 0, 0, 0);
    __syncthreads();                        // protect LDS for next staging
  }

  // epilogue: D layout col = lane&15, row = (lane>>4)*4 + reg  [m89-verified]
  const int dr = (lane >> 4) * 4;
  const int dc = lane & 15;
  float* outb = out + (size_t)b * COUT * TT;
#pragma unroll
  for (int i = 0; i < 4; ++i) {
#pragma unroll
    for (int j = 0; j < 4; ++j) {
      const int mm = m0 + wm + i * 16 + dr;
      const int nn = t0 + wn + j * 16 + dc;
      float* p = outb + (size_t)mm * TT + nn;
#pragma unroll
      for (int r = 0; r < 4; ++r) p[(size_t)r * TT] = acc[i][j][r];
    }
  }
}

extern "C" void kernel_launch(void* const* d_in, const int* in_sizes, int n_in,
                              void* d_out, int out_size, void* d_ws, size_t ws_size,
                              hipStream_t stream) {
  const float* x = (const float*)d_in[0];   // [16, 512, 8192]
  const float* W = (const float*)d_in[1];   // [512, 2048]
  float* out = (float*)d_out;               // [16, 512, 8192]

  // workspace: Wq bf16 [512][2048] (2 MB) then Xtp bf16 [16][8216][512] (~134.6 MB)
  u16* Wq = (u16*)d_ws;
  u16* Xt = (u16*)d_ws + (1u << 20);

  transpose_cast_k<<<dim3(128, 8, 16),  dim3(256), 0, stream>>>(x, Xt);
  wperm_k         <<<dim3(4096),        dim3(256), 0, stream>>>(W, Wq);
  conv_gemm_k     <<<dim3(4096),        dim3(256), 0, stream>>>(Wq, Xt, out);
}